// Round 6
// baseline (386.475 us; speedup 1.0000x reference)
//
#include <hip/hip_runtime.h>
#include <stdint.h>

#define DEV static __device__ __forceinline__

typedef _Float16 half8 __attribute__((ext_vector_type(8)));
typedef _Float16 half4 __attribute__((ext_vector_type(4)));
typedef float f32x4 __attribute__((ext_vector_type(4)));
typedef uint16_t u16x8 __attribute__((ext_vector_type(8)));

// Problem constants (B=2, S=2048, D=2048, H=16, HD=128)
constexpr int Bc = 2, Sc = 2048, Dc = 2048, Hc = 16, HDc = 128;
constexpr int D3c = 3 * Dc;   // 6144
constexpr int Mc = Bc * Sc;   // 4096

// -------- helpers --------
DEV void gl_lds16(const void* g, void* l) {
    // async 16B/lane global->LDS; LDS dest = wave-uniform base + lane*16
    __builtin_amdgcn_global_load_lds(
        (const __attribute__((address_space(1))) unsigned int*)g,
        (__attribute__((address_space(3))) unsigned int*)l,
        16, 0, 0);
}

// ======================= cast fp32 -> fp16 =======================
__global__ __launch_bounds__(256) void cast_f16_kernel(
    const float* __restrict__ in, _Float16* __restrict__ out)
{
    int i = blockIdx.x * 256 + threadIdx.x;          // 8 elems per thread
    const float4* p = (const float4*)in;
    float4 a = p[i * 2], b = p[i * 2 + 1];
    half8 hv;
    hv[0] = (_Float16)a.x; hv[1] = (_Float16)a.y; hv[2] = (_Float16)a.z; hv[3] = (_Float16)a.w;
    hv[4] = (_Float16)b.x; hv[5] = (_Float16)b.y; hv[6] = (_Float16)b.z; hv[7] = (_Float16)b.w;
    *(half8*)(out + (size_t)i * 8) = hv;
}

// ============== transpose + cast: in[R][C] f32 -> out[C][R] f16 ==============
// R2-verified: float4 loads / half8 stores, 16B-chunk XOR swizzle keyed on
// (row>>3)&7 -> all 32 banks covered, 2 lanes each (free).
__global__ __launch_bounds__(256) void transpose_cast_kernel(
    const float* __restrict__ in, _Float16* __restrict__ out, int R, int C)
{
    __shared__ float ls[64][64];                 // 16 KB, chunk-swizzled storage
    const int t = threadIdx.x;
    const int r0 = blockIdx.y * 64, c0 = blockIdx.x * 64;
    {
        const int rr = t >> 4, lc = t & 15;      // logical 16B-chunk index = lc
#pragma unroll
        for (int p = 0; p < 4; ++p) {
            int r = p * 16 + rr;
            int pc = lc ^ ((r >> 3) & 7);
            *(float4*)&ls[r][pc * 4] =
                *(const float4*)&in[(size_t)(r0 + r) * C + c0 + lc * 4];
        }
    }
    __syncthreads();
    {
        const int oc = t >> 3, ss = (t & 7) * 8;
#pragma unroll
        for (int p = 0; p < 2; ++p) {
            int c = p * 32 + oc;
            int lc = c >> 2, wi = c & 3;
            half8 hv;
#pragma unroll
            for (int j = 0; j < 8; ++j) {
                int r = ss + j;
                hv[j] = (_Float16)ls[r][(lc ^ ((r >> 3) & 7)) * 4 + wi];
            }
            *(half8*)&out[(size_t)(c0 + c) * R + r0 + ss] = hv;
        }
    }
}

// ====== V transpose: qkv[b,s, h*384+256+d] -> vt[(bh*128+d)*2048 + s] ======
// R2-verified: u16x8 loads/stores, same chunk-XOR bank fix.
__global__ __launch_bounds__(256) void transpose_v_kernel(
    const uint16_t* __restrict__ qkv, uint16_t* __restrict__ vt)
{
    __shared__ uint16_t ls[64][64];              // 8 KB; 8x 16B chunks per row
    const int t = threadIdx.x;
    const int s0 = blockIdx.x * 64, d0 = blockIdx.y * 64, bh = blockIdx.z;
    const int b = bh >> 4, h = bh & 15;
    {
        const int sr = t >> 3, lc = t & 7;
#pragma unroll
        for (int p = 0; p < 2; ++p) {
            int s = p * 32 + sr;
            int pc = lc ^ ((s >> 3) & 7);
            *(u16x8*)&ls[s][pc * 8] =
                *(const u16x8*)&qkv[(size_t)(b * Sc + s0 + s) * D3c + h * 384 + 256 + d0 + lc * 8];
        }
    }
    __syncthreads();
    {
        const int od = t >> 3, ss = (t & 7) * 8;
#pragma unroll
        for (int p = 0; p < 2; ++p) {
            int d = p * 32 + od;
            int lc = d >> 3, wi = d & 7;
            u16x8 hv;
#pragma unroll
            for (int j = 0; j < 8; ++j) {
                int s = ss + j;
                hv[j] = ls[s][(lc ^ ((s >> 3) & 7)) * 8 + wi];
            }
            *(u16x8*)&vt[(size_t)(bh * HDc + d0 + d) * Sc + s0 + ss] = hv;
        }
    }
}

// ======================= GEMM: C[M,N] = A[M,K] @ Bt[N,K]^T + bias =======================
// ROUND-0-VERIFIED STRUCTURE (104 us, MfmaUtil 48%, FETCH 103MB, 0 conflicts):
// 128x128 tile, BK=64, 256 threads (2x2 waves of 64x64), f16 MFMA 16x16x32,
// global_load_lds staging with XOR-swizzled source pointers, 32KB LDS.
// NO block swizzle: R5 measured that a row-strip XCD remap EXPLODES the
// concurrent per-XCD B-panel footprint (FETCH 107->320MB, +15us). The default
// round-robin dispatch already gives each XCD only 6 distinct B-panels (3MB,
// L2-fits) among resident blocks because 8 | gridDim.x. Leave it alone.
template <int BF16OUT>
__global__ __launch_bounds__(256, 2) void gemm_bt_kernel(
    const _Float16* __restrict__ A, const _Float16* __restrict__ Bt,
    const float* __restrict__ bias, void* __restrict__ Cout,
    int M, int N, int K)
{
    __shared__ __align__(16) char smem[32768];
    char* sA = smem;            // [128 rows][8 chunks16B] swizzled: chunk ^= row&7
    char* sB = smem + 16384;
    const int t = threadIdx.x, w = t >> 6, lane = t & 63;
    const int quad = lane >> 4, l15 = lane & 15;
    const int wr = w >> 1, wc = w & 1;
    const int n0 = blockIdx.x * 128, m0 = blockIdx.y * 128;

    const f32x4 vzero = {0.f, 0.f, 0.f, 0.f};
    f32x4 acc[4][4];
#pragma unroll
    for (int i = 0; i < 4; ++i)
#pragma unroll
        for (int j = 0; j < 4; ++j) acc[i][j] = vzero;

    const int kiters = K >> 6;
    for (int kk = 0; kk < kiters; ++kk) {
#pragma unroll
        for (int i = 0; i < 4; ++i) {
            int c = i * 256 + t;
            int row = c >> 3, kbs = c & 7, kact = kbs ^ (row & 7);
            gl_lds16(A + (size_t)(m0 + row) * K + kk * 64 + kact * 8,
                     sA + (i * 256 + w * 64) * 16);
        }
#pragma unroll
        for (int i = 0; i < 4; ++i) {
            int c = i * 256 + t;
            int row = c >> 3, kbs = c & 7, kact = kbs ^ (row & 7);
            gl_lds16(Bt + (size_t)(n0 + row) * K + kk * 64 + kact * 8,
                     sB + (i * 256 + w * 64) * 16);
        }
        __syncthreads();
#pragma unroll
        for (int ks = 0; ks < 2; ++ks) {
            half8 af[4], bf[4];
#pragma unroll
            for (int mt = 0; mt < 4; ++mt) {
                int row = wr * 64 + mt * 16 + l15;
                int kact = (ks * 4 + quad) ^ (l15 & 7);
                af[mt] = *(const half8*)(sA + row * 128 + kact * 16);
            }
#pragma unroll
            for (int nt = 0; nt < 4; ++nt) {
                int row = wc * 64 + nt * 16 + l15;
                int kact = (ks * 4 + quad) ^ (l15 & 7);
                bf[nt] = *(const half8*)(sB + row * 128 + kact * 16);
            }
#pragma unroll
            for (int mt = 0; mt < 4; ++mt)
#pragma unroll
                for (int nt = 0; nt < 4; ++nt)
                    acc[mt][nt] = __builtin_amdgcn_mfma_f32_16x16x32_f16(
                        af[mt], bf[nt], acc[mt][nt], 0, 0, 0);
        }
        __syncthreads();
    }

    // epilogue: C/D layout col=lane&15, row=quad*4+reg (m89-verified)
#pragma unroll
    for (int nt = 0; nt < 4; ++nt) {
        int col = n0 + wc * 64 + nt * 16 + l15;
        float bv = bias[col];
#pragma unroll
        for (int mt = 0; mt < 4; ++mt)
#pragma unroll
            for (int r = 0; r < 4; ++r) {
                int row = m0 + wr * 64 + mt * 16 + quad * 4 + r;
                float v = acc[mt][nt][r] + bv;
                if (BF16OUT) ((_Float16*)Cout)[(size_t)row * N + col] = (_Float16)v;
                else         ((float*)Cout)[(size_t)row * N + col] = v;
            }
    }
}

// ======================= flash attention (S^T orientation) =======================
// grid (32 bh, 32 qtiles heavy-first); block 256 = 4 waves; BM=64 q rows (16/wave),
// BN=64 kv per iter. S^T = K·Q^T so the C-layout of S^T IS the B-operand layout of
// mfma_16x16x16 -> P^T feeds PV by in-lane f32->f16 pack, no LDS round-trip.
// O^T accumulated in registers; one LDS transpose at epilogue for coalesced store.
// T5 s_setprio(1/0) around both MFMA clusters (kept: R5 delta + m191 +4-7%).
__global__ __launch_bounds__(256, 4) void flash_kernel(
    const _Float16* __restrict__ qkv, const _Float16* __restrict__ vt,
    _Float16* __restrict__ attn)
{
    __shared__ __align__(16) char smem[32768];
    char* sK = smem;            // [64 kv][16 chunks16B] swizzled ^(row&15)
    char* sV = smem + 16384;    // [128 d][8 chunks16B]  swizzled ^(row&7)

    const int t = threadIdx.x, w = t >> 6, lane = t & 63;
    const int quad = lane >> 4, l15 = lane & 15;
    const int bh = blockIdx.x;
    const int qt = 31 - blockIdx.y;          // heavy tiles dispatched first
    const int b = bh >> 4, h = bh & 15;
    const int q0 = qt * 64;
    const int qrow = q0 + w * 16 + l15;      // this lane's q column (S^T orientation)

    // Q fragments straight from global (once per block); B-operand layout == row reads
    half8 qf[4];
#pragma unroll
    for (int ks = 0; ks < 4; ++ks) {
        const _Float16* p = qkv + (size_t)(b * Sc + qrow) * D3c +
                            h * 384 + ks * 32 + quad * 8;
        qf[ks] = *(const half8*)p;
    }

    const f32x4 vzero = {0.f, 0.f, 0.f, 0.f};
    f32x4 o[8];                 // O^T[d = dt*16 + quad*4 + r][q = l15-col]
#pragma unroll
    for (int dt = 0; dt < 8; ++dt) o[dt] = vzero;
    float m_st = -1e30f, l_st = 0.f;   // per-lane stats for q = qrow

    const float kScale = 0.08838834764831845f * 1.4426950408889634f; // 1/sqrt(128)*log2(e)
    const int nkt = qt + 1;

    for (int kt = 0; kt < nkt; ++kt) {
        // ---- stage K tile [64 kv][128 d] ----
#pragma unroll
        for (int i = 0; i < 4; ++i) {
            int c = i * 256 + t;
            int row = c >> 4, kbs = c & 15, kact = kbs ^ (row & 15);
            gl_lds16(qkv + (size_t)(b * Sc + kt * 64 + row) * D3c + h * 384 + 128 + kact * 8,
                     sK + (i * 256 + w * 64) * 16);
        }
        // ---- stage Vt tile [128 d][64 kv] ----
#pragma unroll
        for (int i = 0; i < 4; ++i) {
            int c = i * 256 + t;
            int row = c >> 3, kbs = c & 7, kact = kbs ^ (row & 7);
            gl_lds16(vt + (size_t)(bh * HDc + row) * Sc + kt * 64 + kact * 8,
                     sV + (i * 256 + w * 64) * 16);
        }
        __syncthreads();

        // ---- S^T = K Q^T : D[kv][q], per wave M=64 kv x N=16 q, K=128 d ----
        f32x4 sf[4];
#pragma unroll
        for (int kb = 0; kb < 4; ++kb) sf[kb] = vzero;
        __builtin_amdgcn_s_setprio(1);
#pragma unroll
        for (int ks = 0; ks < 4; ++ks) {
#pragma unroll
            for (int kb = 0; kb < 4; ++kb) {
                int row = kb * 16 + l15;
                int slot = (ks * 4 + quad) ^ l15;
                half8 kf = *(const half8*)(sK + row * 256 + slot * 16);
                sf[kb] = __builtin_amdgcn_mfma_f32_16x16x32_f16(kf, qf[ks], sf[kb], 0, 0, 0);
            }
        }
        __builtin_amdgcn_s_setprio(0);

        // ---- online softmax: lane owns one q column (q=qrow), kv = kb*16+quad*4+r ----
        const bool domask = (kt == qt);
        float rm = -1e30f;
#pragma unroll
        for (int kb = 0; kb < 4; ++kb)
#pragma unroll
            for (int r = 0; r < 4; ++r) {
                float v = sf[kb][r] * kScale;
                if (domask) {
                    int col = kt * 64 + kb * 16 + quad * 4 + r;
                    if (col > qrow) v = -1e30f;
                }
                sf[kb][r] = v;
                rm = fmaxf(rm, v);
            }
        // reduce max across the 4 quads holding this q column
        rm = fmaxf(rm, __shfl_xor(rm, 16, 64));
        rm = fmaxf(rm, __shfl_xor(rm, 32, 64));
        float mn = fmaxf(m_st, rm);
        float alpha = __builtin_amdgcn_exp2f(m_st - mn);
        m_st = mn;

        // P^T pack: exp2(s-m) -> f16; C-layout(kv=quad*4+r) == B-layout(k=quad*4+j)
        half4 pb[4];
        float rs = 0.f;
#pragma unroll
        for (int kb = 0; kb < 4; ++kb)
#pragma unroll
            for (int r = 0; r < 4; ++r) {
                float p = __builtin_amdgcn_exp2f(sf[kb][r] - mn);
                rs += p;
                pb[kb][r] = (_Float16)p;
            }
        rs += __shfl_xor(rs, 16, 64);
        rs += __shfl_xor(rs, 32, 64);
        l_st = l_st * alpha + rs;

        // rescale O^T (alpha is per-lane scalar: all o elements share q=qrow)
#pragma unroll
        for (int dt = 0; dt < 8; ++dt)
#pragma unroll
            for (int r = 0; r < 4; ++r) o[dt][r] *= alpha;

        // ---- O^T += V^T P^T (mfma 16x16x16: A=V^T rows, B=P^T in-register) ----
        __builtin_amdgcn_s_setprio(1);
#pragma unroll
        for (int kb = 0; kb < 4; ++kb) {
#pragma unroll
            for (int dt = 0; dt < 8; ++dt) {
                int row = dt * 16 + l15;
                int slot = (kb * 2 + (quad >> 1)) ^ (l15 & 7);
                half4 vf = *(const half4*)(sV + row * 128 + slot * 16 + (quad & 1) * 8);
                o[dt] = __builtin_amdgcn_mfma_f32_16x16x16f16(vf, pb[kb], o[dt], 0, 0, 0);
            }
        }
        __builtin_amdgcn_s_setprio(0);
        __syncthreads();   // LDS reads done before restaging
    }

    // ---- epilogue: O^T/l -> LDS transpose -> coalesced f16 store ----
    char* sO = smem;      // [64 q][272B rows] (17x16B, conflict-shifted, 16B-aligned)
    float linv = 1.0f / l_st;
#pragma unroll
    for (int dt = 0; dt < 8; ++dt) {
        half4 hv;
#pragma unroll
        for (int r = 0; r < 4; ++r) hv[r] = (_Float16)(o[dt][r] * linv);
        *(half4*)(sO + (w * 16 + l15) * 272 + (dt * 16 + quad * 4) * 2) = hv;
    }
    __syncthreads();
#pragma unroll
    for (int i = 0; i < 4; ++i) {
        int q = i * 16 + (t >> 4);
        int d = (t & 15) * 8;
        half8 hv = *(const half8*)(sO + q * 272 + d * 2);
        *(half8*)(attn + (size_t)(b * Sc + q0 + q) * Dc + h * HDc + d) = hv;
    }
}

// ======================= launch =======================
extern "C" void kernel_launch(void* const* d_in, const int* in_sizes, int n_in,
                              void* d_out, int out_size, void* d_ws, size_t ws_size,
                              hipStream_t stream)
{
    (void)in_sizes; (void)n_in; (void)out_size; (void)ws_size;
    const float* x    = (const float*)d_in[0];
    const float* Wqkv = (const float*)d_in[1];
    const float* bqkv = (const float*)d_in[2];
    const float* Wo   = (const float*)d_in[3];
    const float* bo   = (const float*)d_in[4];
    float* out = (float*)d_out;

    // workspace layout (f16 elems); attn aliases xb, vtg aliases wt1 (both dead by then)
    _Float16* xb  = (_Float16*)d_ws;                   // 4096*2048
    _Float16* wt1 = xb  + (size_t)Mc * Dc;             // 6144*2048 (Wqkv^T)
    _Float16* wt2 = wt1 + (size_t)D3c * Dc;            // 2048*2048 (Wo^T)
    _Float16* qkv = wt2 + (size_t)Dc * Dc;             // 4096*6144
    _Float16* vtg  = wt1;                              // 32*128*2048 (V^T), reuses wt1
    _Float16* attn = xb;                               // 4096*2048, reuses xb

    cast_f16_kernel<<<Mc * Dc / 2048, 256, 0, stream>>>(x, xb);
    transpose_cast_kernel<<<dim3(D3c / 64, Dc / 64), 256, 0, stream>>>(Wqkv, wt1, Dc, D3c);
    transpose_cast_kernel<<<dim3(Dc / 64, Dc / 64), 256, 0, stream>>>(Wo, wt2, Dc, Dc);
    gemm_bt_kernel<1><<<dim3(D3c / 128, Mc / 128), 256, 0, stream>>>(
        xb, wt1, bqkv, qkv, Mc, D3c, Dc);
    transpose_v_kernel<<<dim3(Sc / 64, 2, Bc * Hc), 256, 0, stream>>>(
        (const uint16_t*)qkv, (uint16_t*)vtg);
    flash_kernel<<<dim3(Bc * Hc, 32), 256, 0, stream>>>(qkv, vtg, attn);
    gemm_bt_kernel<0><<<dim3(Dc / 128, Mc / 128), 256, 0, stream>>>(
        attn, wt2, bo, out, Mc, Dc, Dc);
}

// Round 7
// 360.397 us; speedup vs baseline: 1.0724x; 1.0724x over previous
//
#include <hip/hip_runtime.h>
#include <stdint.h>

#define DEV static __device__ __forceinline__

typedef _Float16 half8 __attribute__((ext_vector_type(8)));
typedef _Float16 half4 __attribute__((ext_vector_type(4)));
typedef float f32x4 __attribute__((ext_vector_type(4)));
typedef uint16_t u16x8 __attribute__((ext_vector_type(8)));

// Problem constants (B=2, S=2048, D=2048, H=16, HD=128)
constexpr int Bc = 2, Sc = 2048, Dc = 2048, Hc = 16, HDc = 128;
constexpr int D3c = 3 * Dc;   // 6144
constexpr int Mc = Bc * Sc;   // 4096

// -------- helpers --------
DEV void gl_lds16(const void* g, void* l) {
    // async 16B/lane global->LDS; LDS dest = wave-uniform base + lane*16
    __builtin_amdgcn_global_load_lds(
        (const __attribute__((address_space(1))) unsigned int*)g,
        (__attribute__((address_space(3))) unsigned int*)l,
        16, 0, 0);
}

// ======================= fused prep: cast x + transpose both W ===============
// One dispatch instead of three (launch-gap reduction). Block-granular branch:
//   id <  4096          : cast x (f32 -> f16), 2048 elems/block
//   id <  4096+3072     : transpose Wqkv [2048 x 6144] -> wt1 [6144 x 2048]
//   else (1024 blocks)  : transpose Wo   [2048 x 2048] -> wt2 [2048 x 2048]
// Transpose body = R2-verified float4/half8 + 16B-chunk XOR bank swizzle.
DEV void transpose_tile(const float* __restrict__ in, _Float16* __restrict__ out,
                        int R, int C, int bx, int by, int t)
{
    __shared__ float ls[64][64];                 // 16 KB, chunk-swizzled storage
    const int r0 = by * 64, c0 = bx * 64;
    {
        const int rr = t >> 4, lc = t & 15;
#pragma unroll
        for (int p = 0; p < 4; ++p) {
            int r = p * 16 + rr;
            int pc = lc ^ ((r >> 3) & 7);
            *(float4*)&ls[r][pc * 4] =
                *(const float4*)&in[(size_t)(r0 + r) * C + c0 + lc * 4];
        }
    }
    __syncthreads();
    {
        const int oc = t >> 3, ss = (t & 7) * 8;
#pragma unroll
        for (int p = 0; p < 2; ++p) {
            int c = p * 32 + oc;
            int lc = c >> 2, wi = c & 3;
            half8 hv;
#pragma unroll
            for (int j = 0; j < 8; ++j) {
                int r = ss + j;
                hv[j] = (_Float16)ls[r][(lc ^ ((r >> 3) & 7)) * 4 + wi];
            }
            *(half8*)&out[(size_t)(c0 + c) * R + r0 + ss] = hv;
        }
    }
}

__global__ __launch_bounds__(256) void prep_kernel(
    const float* __restrict__ x, const float* __restrict__ Wqkv,
    const float* __restrict__ Wo,
    _Float16* __restrict__ xb, _Float16* __restrict__ wt1,
    _Float16* __restrict__ wt2)
{
    const int id = blockIdx.x, t = threadIdx.x;
    if (id < 4096) {
        // cast 2048 f32 -> f16 per block, 8 per thread
        int i = id * 256 + t;
        const float4* p = (const float4*)x;
        float4 a = p[i * 2], b = p[i * 2 + 1];
        half8 hv;
        hv[0] = (_Float16)a.x; hv[1] = (_Float16)a.y; hv[2] = (_Float16)a.z; hv[3] = (_Float16)a.w;
        hv[4] = (_Float16)b.x; hv[5] = (_Float16)b.y; hv[6] = (_Float16)b.z; hv[7] = (_Float16)b.w;
        *(half8*)(xb + (size_t)i * 8) = hv;
    } else if (id < 4096 + 3072) {
        int id2 = id - 4096;                    // grid was (96 x, 32 y)
        transpose_tile(Wqkv, wt1, Dc, D3c, id2 % 96, id2 / 96, t);
    } else {
        int id3 = id - 7168;                    // grid was (32 x, 32 y)
        transpose_tile(Wo, wt2, Dc, Dc, id3 & 31, id3 >> 5, t);
    }
}

// ====== V transpose: qkv[b,s, h*384+256+d] -> vt[(bh*128+d)*2048 + s] ======
// R2-verified: u16x8 loads/stores, chunk-XOR bank fix.
__global__ __launch_bounds__(256) void transpose_v_kernel(
    const uint16_t* __restrict__ qkv, uint16_t* __restrict__ vt)
{
    __shared__ uint16_t ls[64][64];              // 8 KB; 8x 16B chunks per row
    const int t = threadIdx.x;
    const int s0 = blockIdx.x * 64, d0 = blockIdx.y * 64, bh = blockIdx.z;
    const int b = bh >> 4, h = bh & 15;
    {
        const int sr = t >> 3, lc = t & 7;
#pragma unroll
        for (int p = 0; p < 2; ++p) {
            int s = p * 32 + sr;
            int pc = lc ^ ((s >> 3) & 7);
            *(u16x8*)&ls[s][pc * 8] =
                *(const u16x8*)&qkv[(size_t)(b * Sc + s0 + s) * D3c + h * 384 + 256 + d0 + lc * 8];
        }
    }
    __syncthreads();
    {
        const int od = t >> 3, ss = (t & 7) * 8;
#pragma unroll
        for (int p = 0; p < 2; ++p) {
            int d = p * 32 + od;
            int lc = d >> 3, wi = d & 7;
            u16x8 hv;
#pragma unroll
            for (int j = 0; j < 8; ++j) {
                int s = ss + j;
                hv[j] = ls[s][(lc ^ ((s >> 3) & 7)) * 8 + wi];
            }
            *(u16x8*)&vt[(size_t)(bh * HDc + d0 + d) * Sc + s0 + ss] = hv;
        }
    }
}

// ======================= GEMM: C[M,N] = A[M,K] @ Bt[N,K]^T + bias =======================
// FROZEN R0-VERIFIED STRUCTURE (105 us, MfmaUtil 48%, FETCH 103MB, 0 conflicts):
// 128x128 tile, BK=64, 256 threads (2x2 waves of 64x64), f16 MFMA 16x16x32,
// global_load_lds staging with XOR-swizzled source pointers, 32KB LDS,
// ~2.6 blocks/CU. No block swizzle (R5: row-strip XCD remap exploded the
// per-XCD B-panel footprint, FETCH 107->320MB). Structural pipelining attempts
// (ring-3/BK32 R1, dbuf R2, 8-wave 2-phase R4) all lost to this -- parked.
template <int BF16OUT>
__global__ __launch_bounds__(256, 2) void gemm_bt_kernel(
    const _Float16* __restrict__ A, const _Float16* __restrict__ Bt,
    const float* __restrict__ bias, void* __restrict__ Cout,
    int M, int N, int K)
{
    __shared__ __align__(16) char smem[32768];
    char* sA = smem;            // [128 rows][8 chunks16B] swizzled: chunk ^= row&7
    char* sB = smem + 16384;
    const int t = threadIdx.x, w = t >> 6, lane = t & 63;
    const int quad = lane >> 4, l15 = lane & 15;
    const int wr = w >> 1, wc = w & 1;
    const int n0 = blockIdx.x * 128, m0 = blockIdx.y * 128;

    const f32x4 vzero = {0.f, 0.f, 0.f, 0.f};
    f32x4 acc[4][4];
#pragma unroll
    for (int i = 0; i < 4; ++i)
#pragma unroll
        for (int j = 0; j < 4; ++j) acc[i][j] = vzero;

    const int kiters = K >> 6;
    for (int kk = 0; kk < kiters; ++kk) {
#pragma unroll
        for (int i = 0; i < 4; ++i) {
            int c = i * 256 + t;
            int row = c >> 3, kbs = c & 7, kact = kbs ^ (row & 7);
            gl_lds16(A + (size_t)(m0 + row) * K + kk * 64 + kact * 8,
                     sA + (i * 256 + w * 64) * 16);
        }
#pragma unroll
        for (int i = 0; i < 4; ++i) {
            int c = i * 256 + t;
            int row = c >> 3, kbs = c & 7, kact = kbs ^ (row & 7);
            gl_lds16(Bt + (size_t)(n0 + row) * K + kk * 64 + kact * 8,
                     sB + (i * 256 + w * 64) * 16);
        }
        __syncthreads();
#pragma unroll
        for (int ks = 0; ks < 2; ++ks) {
            half8 af[4], bf[4];
#pragma unroll
            for (int mt = 0; mt < 4; ++mt) {
                int row = wr * 64 + mt * 16 + l15;
                int kact = (ks * 4 + quad) ^ (l15 & 7);
                af[mt] = *(const half8*)(sA + row * 128 + kact * 16);
            }
#pragma unroll
            for (int nt = 0; nt < 4; ++nt) {
                int row = wc * 64 + nt * 16 + l15;
                int kact = (ks * 4 + quad) ^ (l15 & 7);
                bf[nt] = *(const half8*)(sB + row * 128 + kact * 16);
            }
#pragma unroll
            for (int mt = 0; mt < 4; ++mt)
#pragma unroll
                for (int nt = 0; nt < 4; ++nt)
                    acc[mt][nt] = __builtin_amdgcn_mfma_f32_16x16x32_f16(
                        af[mt], bf[nt], acc[mt][nt], 0, 0, 0);
        }
        __syncthreads();
    }

    // epilogue: C/D layout col=lane&15, row=quad*4+reg (m89-verified)
#pragma unroll
    for (int nt = 0; nt < 4; ++nt) {
        int col = n0 + wc * 64 + nt * 16 + l15;
        float bv = bias[col];
#pragma unroll
        for (int mt = 0; mt < 4; ++mt)
#pragma unroll
            for (int r = 0; r < 4; ++r) {
                int row = m0 + wr * 64 + mt * 16 + quad * 4 + r;
                float v = acc[mt][nt][r] + bv;
                if (BF16OUT) ((_Float16*)Cout)[(size_t)row * N + col] = (_Float16)v;
                else         ((float*)Cout)[(size_t)row * N + col] = v;
            }
    }
}

// ======================= flash attention (S^T orientation, QBLK=128) ===========
// grid (32 bh, 16 q-blocks); block 512 = 8 waves, each owning 16 q rows.
// Per iter: ONE 64kv x 128d K tile + V^T tile serve all 128 q rows -> staging
// traffic and barrier count HALVED vs QBLK=64. Per-wave inner structure
// unchanged from the verified QBLK=64 kernel (same LDS layouts, same fragment
// reads, same softmax). qt remap pairs heavy+light blocks per CU (2 blocks/CU,
// work sum constant). setprio dropped: barrier-lockstep regime (m190-negative).
__global__ __launch_bounds__(512, 4) void flash_kernel(
    const _Float16* __restrict__ qkv, const _Float16* __restrict__ vt,
    _Float16* __restrict__ attn)
{
    __shared__ __align__(16) char smem[36864];
    char* sK = smem;            // [64 kv][16 chunks16B] swizzled ^(row&15)
    char* sV = smem + 16384;    // [128 d][8 chunks16B]  swizzled ^(row&7)

    const int t = threadIdx.x, w = t >> 6, lane = t & 63;   // w in 0..7
    const int quad = lane >> 4, l15 = lane & 15;
    const int bh = blockIdx.x;
    const int by = blockIdx.y;
    const int qt = (by < 8) ? 15 - by : by - 8;   // heavy-first + balanced pairs
    const int b = bh >> 4, h = bh & 15;
    const int q0 = qt * 128;
    const int qrow = q0 + w * 16 + l15;      // this lane's q column (S^T orientation)

    // Q fragments straight from global (once per block)
    half8 qf[4];
#pragma unroll
    for (int ks = 0; ks < 4; ++ks) {
        const _Float16* p = qkv + (size_t)(b * Sc + qrow) * D3c +
                            h * 384 + ks * 32 + quad * 8;
        qf[ks] = *(const half8*)p;
    }

    const f32x4 vzero = {0.f, 0.f, 0.f, 0.f};
    f32x4 o[8];                 // O^T[d = dt*16 + quad*4 + r][q = l15-col]
#pragma unroll
    for (int dt = 0; dt < 8; ++dt) o[dt] = vzero;
    float m_st = -1e30f, l_st = 0.f;   // per-lane stats for q = qrow

    const float kScale = 0.08838834764831845f * 1.4426950408889634f; // 1/sqrt(128)*log2(e)
    const int nkt = 2 * qt + 2;

    for (int kt = 0; kt < nkt; ++kt) {
        // ---- stage K tile [64 kv][128 d]: 1024 chunks over 512 threads ----
#pragma unroll
        for (int i = 0; i < 2; ++i) {
            int c = i * 512 + t;
            int row = c >> 4, kbs = c & 15, kact = kbs ^ (row & 15);
            gl_lds16(qkv + (size_t)(b * Sc + kt * 64 + row) * D3c + h * 384 + 128 + kact * 8,
                     sK + (i * 512 + w * 64) * 16);
        }
        // ---- stage Vt tile [128 d][64 kv] ----
#pragma unroll
        for (int i = 0; i < 2; ++i) {
            int c = i * 512 + t;
            int row = c >> 3, kbs = c & 7, kact = kbs ^ (row & 7);
            gl_lds16(vt + (size_t)(bh * HDc + row) * Sc + kt * 64 + kact * 8,
                     sV + (i * 512 + w * 64) * 16);
        }
        __syncthreads();

        // ---- S^T = K Q^T : per wave M=64 kv x N=16 q, K=128 d ----
        f32x4 sf[4];
#pragma unroll
        for (int kb = 0; kb < 4; ++kb) sf[kb] = vzero;
#pragma unroll
        for (int ks = 0; ks < 4; ++ks) {
#pragma unroll
            for (int kb = 0; kb < 4; ++kb) {
                int row = kb * 16 + l15;
                int slot = (ks * 4 + quad) ^ l15;
                half8 kf = *(const half8*)(sK + row * 256 + slot * 16);
                sf[kb] = __builtin_amdgcn_mfma_f32_16x16x32_f16(kf, qf[ks], sf[kb], 0, 0, 0);
            }
        }

        // ---- online softmax: lane owns q=qrow, kv = kt*64 + kb*16+quad*4+r ----
        const bool domask = (kt >= 2 * qt);   // tiles overlapping the diagonal
        float rm = -1e30f;
#pragma unroll
        for (int kb = 0; kb < 4; ++kb)
#pragma unroll
            for (int r = 0; r < 4; ++r) {
                float v = sf[kb][r] * kScale;
                if (domask) {
                    int col = kt * 64 + kb * 16 + quad * 4 + r;
                    if (col > qrow) v = -1e30f;
                }
                sf[kb][r] = v;
                rm = fmaxf(rm, v);
            }
        rm = fmaxf(rm, __shfl_xor(rm, 16, 64));
        rm = fmaxf(rm, __shfl_xor(rm, 32, 64));
        float mn = fmaxf(m_st, rm);
        float alpha = __builtin_amdgcn_exp2f(m_st - mn);
        m_st = mn;

        // P^T pack: exp2(s-m) -> f16; C-layout(kv=quad*4+r) == B-layout(k=quad*4+j)
        half4 pb[4];
        float rs = 0.f;
#pragma unroll
        for (int kb = 0; kb < 4; ++kb)
#pragma unroll
            for (int r = 0; r < 4; ++r) {
                float p = __builtin_amdgcn_exp2f(sf[kb][r] - mn);
                rs += p;
                pb[kb][r] = (_Float16)p;
            }
        rs += __shfl_xor(rs, 16, 64);
        rs += __shfl_xor(rs, 32, 64);
        l_st = l_st * alpha + rs;

        // rescale O^T (alpha per-lane scalar: all o elements share q=qrow)
#pragma unroll
        for (int dt = 0; dt < 8; ++dt)
#pragma unroll
            for (int r = 0; r < 4; ++r) o[dt][r] *= alpha;

        // ---- O^T += V^T P^T (mfma 16x16x16: A=V^T rows, B=P^T in-register) ----
#pragma unroll
        for (int kb = 0; kb < 4; ++kb) {
#pragma unroll
            for (int dt = 0; dt < 8; ++dt) {
                int row = dt * 16 + l15;
                int slot = (kb * 2 + (quad >> 1)) ^ (l15 & 7);
                half4 vf = *(const half4*)(sV + row * 128 + slot * 16 + (quad & 1) * 8);
                o[dt] = __builtin_amdgcn_mfma_f32_16x16x16f16(vf, pb[kb], o[dt], 0, 0, 0);
            }
        }
        __syncthreads();   // LDS reads done before restaging
    }

    // ---- epilogue: O^T/l -> LDS transpose -> coalesced f16 store ----
    char* sO = smem;      // [128 q][272B rows] (17x16B, conflict-shifted) = 34816B
    float linv = 1.0f / l_st;
#pragma unroll
    for (int dt = 0; dt < 8; ++dt) {
        half4 hv;
#pragma unroll
        for (int r = 0; r < 4; ++r) hv[r] = (_Float16)(o[dt][r] * linv);
        *(half4*)(sO + (w * 16 + l15) * 272 + (dt * 16 + quad * 4) * 2) = hv;
    }
    __syncthreads();
#pragma unroll
    for (int i = 0; i < 4; ++i) {
        int q = i * 32 + (t >> 4);
        int d = (t & 15) * 8;
        half8 hv = *(const half8*)(sO + q * 272 + d * 2);
        *(half8*)(attn + (size_t)(b * Sc + q0 + q) * Dc + h * HDc + d) = hv;
    }
}

// ======================= launch =======================
extern "C" void kernel_launch(void* const* d_in, const int* in_sizes, int n_in,
                              void* d_out, int out_size, void* d_ws, size_t ws_size,
                              hipStream_t stream)
{
    (void)in_sizes; (void)n_in; (void)out_size; (void)ws_size;
    const float* x    = (const float*)d_in[0];
    const float* Wqkv = (const float*)d_in[1];
    const float* bqkv = (const float*)d_in[2];
    const float* Wo   = (const float*)d_in[3];
    const float* bo   = (const float*)d_in[4];
    float* out = (float*)d_out;

    // workspace layout (f16 elems); attn aliases xb, vtg aliases wt1 (both dead by then)
    _Float16* xb  = (_Float16*)d_ws;                   // 4096*2048
    _Float16* wt1 = xb  + (size_t)Mc * Dc;             // 6144*2048 (Wqkv^T)
    _Float16* wt2 = wt1 + (size_t)D3c * Dc;            // 2048*2048 (Wo^T)
    _Float16* qkv = wt2 + (size_t)Dc * Dc;             // 4096*6144
    _Float16* vtg  = wt1;                              // 32*128*2048 (V^T), reuses wt1
    _Float16* attn = xb;                               // 4096*2048, reuses xb

    prep_kernel<<<8192, 256, 0, stream>>>(x, Wqkv, Wo, xb, wt1, wt2);
    gemm_bt_kernel<1><<<dim3(D3c / 128, Mc / 128), 256, 0, stream>>>(
        xb, wt1, bqkv, qkv, Mc, D3c, Dc);
    transpose_v_kernel<<<dim3(Sc / 64, 2, Bc * Hc), 256, 0, stream>>>(
        (const uint16_t*)qkv, (uint16_t*)vtg);
    flash_kernel<<<dim3(Bc * Hc, 16), 512, 0, stream>>>(qkv, vtg, attn);
    gemm_bt_kernel<0><<<dim3(Dc / 128, Mc / 128), 256, 0, stream>>>(
        attn, wt2, bo, out, Mc, Dc, Dc);
}